// Round 6
// baseline (263.042 us; speedup 1.0000x reference)
//
#include <hip/hip_runtime.h>

// VQ straight-through: B=32, V=4096, D=64, K=512. N = 131072 rows.
// Outputs (flat, concatenated): z_q_st [N,D] f32, z_q [N,D] f32, indices [N] (as f32).
//
// Correctness contract (passing since R2): replicate numpy fp32 bitwise —
//  - sums of squares: numpy pairwise_sum scalar 8-accumulator order (acc = d%8,
//    terms d-ascending), products rounded separately (freeze blocks contraction)
//  - z@e.T dots: sequential single-accumulator FMA chain over d=0..63 (BLAS)
//  - d2 = fl(fl(A - 2*dot) + C) via fmaf(-2,a,A)+C (2a exact); argmin strict <,
//    k ascending (np first-min)
//
// R6 vs R5 (main 175 us, VALUBusy 70%, VGPR 40): R3/R4/R5 proved the compiler
// will NOT keep z[64] register-resident (hints and asm pins both failed); it
// reloads the row from L2 every k-group (~200+ cyc exposed). So move z to LDS:
//  - block's 64 rows staged once, coalesced, stride 68 dwords (16B-aligned,
//    b128 reads spread uniformly over all 32 banks = 8-phase minimum).
//  - 8 codes per k-group (8 FMA chains): 16 ds_read_b128 per 1104 VALU cyc
//    keeps the shared LDS pipe at ~0.7x capacity (4 codes would oversubscribe).
//  - norms kernel rewritten: 8 blocks x 64 lanes, coalesced f4 loads -> LDS
//    (stride 65, 2-way = free) -> per-lane np-order norm (~3 us vs ~25).

#define VQ_N (32 * 4096)
#define VQ_D 64
#define VQ_K 512
#define ZSTRIDE 68  // dwords: 272 B rows, 16B-aligned, uniform bank spread

// Rounding barrier: forbids FMA contraction / reassociation through x.
__device__ __forceinline__ float freeze(float x) {
  asm volatile("" : "+v"(x));
  return x;
}

// ---- kernel 1: C_k = np.sum(emb*emb, -1) in numpy fp32 order ----
// 8 blocks x 64 threads; block b covers codes [64b, 64b+64).
__global__ __launch_bounds__(64) void vq_norms_kernel(
    const float* __restrict__ emb, float* __restrict__ nrm) {
  __shared__ float s_e[64 * 65];  // stride 65: scalar reads 2-way (free)
  const int t = threadIdx.x;
  const float4* src = (const float4*)(emb + (size_t)blockIdx.x * 64 * VQ_D);
#pragma unroll
  for (int j = 0; j < 16; ++j) {
    int idx = j * 64 + t;          // coalesced: consecutive lanes consecutive
    float4 v = src[idx];
    int r = idx >> 4, c = idx & 15;
    float* p = s_e + r * 65 + 4 * c;
    p[0] = v.x; p[1] = v.y; p[2] = v.z; p[3] = v.w;
  }
  __syncthreads();
  const float* e = s_e + t * 65;
  float r0 = freeze(e[0] * e[0]), r1 = freeze(e[1] * e[1]);
  float r2 = freeze(e[2] * e[2]), r3 = freeze(e[3] * e[3]);
  float r4 = freeze(e[4] * e[4]), r5 = freeze(e[5] * e[5]);
  float r6 = freeze(e[6] * e[6]), r7 = freeze(e[7] * e[7]);
#pragma unroll
  for (int i = 8; i < VQ_D; i += 8) {
    r0 += freeze(e[i + 0] * e[i + 0]); r1 += freeze(e[i + 1] * e[i + 1]);
    r2 += freeze(e[i + 2] * e[i + 2]); r3 += freeze(e[i + 3] * e[i + 3]);
    r4 += freeze(e[i + 4] * e[i + 4]); r5 += freeze(e[i + 5] * e[i + 5]);
    r6 += freeze(e[i + 6] * e[i + 6]); r7 += freeze(e[i + 7] * e[i + 7]);
  }
  nrm[blockIdx.x * 64 + t] = ((r0 + r1) + (r2 + r3)) + ((r4 + r5) + (r6 + r7));
}

// ---- kernel 2: main — 64 rows/block in LDS, K split across 4 waves ----
__global__ __launch_bounds__(256) void vq_main_kernel(
    const float* __restrict__ z_e, const float* __restrict__ emb,
    const float* __restrict__ nrm, float* __restrict__ out_st,
    float* __restrict__ out_q, float* __restrict__ out_idx) {
  __shared__ float s_z[64 * ZSTRIDE];  // 17408 B
  __shared__ float s_val[256];
  __shared__ int s_idx[256];
  __shared__ int s_best[64];

  const int tid = threadIdx.x;
  const int lane = tid & 63;                                   // row in block
  const int chunk = __builtin_amdgcn_readfirstlane(tid >> 6);  // wave-uniform
  const int row = blockIdx.x * 64 + lane;

  // ---- stage the block's 64 rows into LDS (coalesced global f4 reads) ----
  const float4* zg = (const float4*)(z_e + (size_t)blockIdx.x * 64 * VQ_D);
#pragma unroll
  for (int j = 0; j < 4; ++j) {
    int idx = j * 256 + tid;  // coalesced
    float4 v = zg[idx];
    int r = idx >> 4, c = idx & 15;
    *(float4*)(s_z + r * ZSTRIDE + 4 * c) = v;  // 272r+16c: 16B-aligned
  }
  __syncthreads();

  const float* zr = s_z + lane * ZSTRIDE;

  // ---- A = np.sum(z*z): acc index d%8, terms d-ascending, rounded products.
  // (r=0 then r+=p[d] is exact for the first term, same as r=p[d].)
  float q0 = 0.f, q1 = 0.f, q2 = 0.f, q3 = 0.f;
  float q4 = 0.f, q5 = 0.f, q6 = 0.f, q7 = 0.f;
#pragma unroll
  for (int j = 0; j < 16; ++j) {
    float4 v = *(const float4*)(zr + 4 * j);
    if ((j & 1) == 0) {
      q0 += freeze(v.x * v.x); q1 += freeze(v.y * v.y);
      q2 += freeze(v.z * v.z); q3 += freeze(v.w * v.w);
    } else {
      q4 += freeze(v.x * v.x); q5 += freeze(v.y * v.y);
      q6 += freeze(v.z * v.z); q7 += freeze(v.w * v.w);
    }
  }
  const float A = ((q0 + q1) + (q2 + q3)) + ((q4 + q5) + (q6 + q7));

  // ---- scan this wave's 128 codes, 8 at a time (8 independent FMA chains) ----
  const int k0 = chunk * (VQ_K / 4);
  float bestv = 3.4e38f;
  int best = k0;
  for (int kk = k0; kk < k0 + VQ_K / 4; kk += 8) {
    const float* e0 = emb + (size_t)(kk + 0) * VQ_D;
    const float* e1 = emb + (size_t)(kk + 1) * VQ_D;
    const float* e2 = emb + (size_t)(kk + 2) * VQ_D;
    const float* e3 = emb + (size_t)(kk + 3) * VQ_D;
    const float* e4 = emb + (size_t)(kk + 4) * VQ_D;
    const float* e5 = emb + (size_t)(kk + 5) * VQ_D;
    const float* e6 = emb + (size_t)(kk + 6) * VQ_D;
    const float* e7 = emb + (size_t)(kk + 7) * VQ_D;
    float a0 = 0.f, a1 = 0.f, a2 = 0.f, a3 = 0.f;
    float a4 = 0.f, a5 = 0.f, a6 = 0.f, a7 = 0.f;
#pragma unroll
    for (int j = 0; j < 16; ++j) {
      float4 zv = *(const float4*)(zr + 4 * j);  // 1 ds_read_b128 -> 32 FMAs
      const int d = 4 * j;
      a0 = fmaf(zv.x, e0[d + 0], a0); a1 = fmaf(zv.x, e1[d + 0], a1);
      a2 = fmaf(zv.x, e2[d + 0], a2); a3 = fmaf(zv.x, e3[d + 0], a3);
      a4 = fmaf(zv.x, e4[d + 0], a4); a5 = fmaf(zv.x, e5[d + 0], a5);
      a6 = fmaf(zv.x, e6[d + 0], a6); a7 = fmaf(zv.x, e7[d + 0], a7);
      a0 = fmaf(zv.y, e0[d + 1], a0); a1 = fmaf(zv.y, e1[d + 1], a1);
      a2 = fmaf(zv.y, e2[d + 1], a2); a3 = fmaf(zv.y, e3[d + 1], a3);
      a4 = fmaf(zv.y, e4[d + 1], a4); a5 = fmaf(zv.y, e5[d + 1], a5);
      a6 = fmaf(zv.y, e6[d + 1], a6); a7 = fmaf(zv.y, e7[d + 1], a7);
      a0 = fmaf(zv.z, e0[d + 2], a0); a1 = fmaf(zv.z, e1[d + 2], a1);
      a2 = fmaf(zv.z, e2[d + 2], a2); a3 = fmaf(zv.z, e3[d + 2], a3);
      a4 = fmaf(zv.z, e4[d + 2], a4); a5 = fmaf(zv.z, e5[d + 2], a5);
      a6 = fmaf(zv.z, e6[d + 2], a6); a7 = fmaf(zv.z, e7[d + 2], a7);
      a0 = fmaf(zv.w, e0[d + 3], a0); a1 = fmaf(zv.w, e1[d + 3], a1);
      a2 = fmaf(zv.w, e2[d + 3], a2); a3 = fmaf(zv.w, e3[d + 3], a3);
      a4 = fmaf(zv.w, e4[d + 3], a4); a5 = fmaf(zv.w, e5[d + 3], a5);
      a6 = fmaf(zv.w, e6[d + 3], a6); a7 = fmaf(zv.w, e7[d + 3], a7);
    }
    // d2 = fl(fl(A - 2*dot) + C); 2*dot exact => fmaf(-2,a,A) == fl(A-2a).
    float t0 = fmaf(-2.0f, a0, A) + nrm[kk + 0];
    float t1 = fmaf(-2.0f, a1, A) + nrm[kk + 1];
    float t2 = fmaf(-2.0f, a2, A) + nrm[kk + 2];
    float t3 = fmaf(-2.0f, a3, A) + nrm[kk + 3];
    float t4 = fmaf(-2.0f, a4, A) + nrm[kk + 4];
    float t5 = fmaf(-2.0f, a5, A) + nrm[kk + 5];
    float t6 = fmaf(-2.0f, a6, A) + nrm[kk + 6];
    float t7 = fmaf(-2.0f, a7, A) + nrm[kk + 7];
    // np.argmin: first strict minimum, k ascending.
    if (t0 < bestv) { bestv = t0; best = kk + 0; }
    if (t1 < bestv) { bestv = t1; best = kk + 1; }
    if (t2 < bestv) { bestv = t2; best = kk + 2; }
    if (t3 < bestv) { bestv = t3; best = kk + 3; }
    if (t4 < bestv) { bestv = t4; best = kk + 4; }
    if (t5 < bestv) { bestv = t5; best = kk + 5; }
    if (t6 < bestv) { bestv = t6; best = kk + 6; }
    if (t7 < bestv) { bestv = t7; best = kk + 7; }
  }

  s_val[chunk * 64 + lane] = bestv;
  s_idx[chunk * 64 + lane] = best;
  __syncthreads();

  // Cross-chunk argmin per row: ascending chunk order + strict < keeps the
  // lowest-index minimum (chunk c's indices all < chunk c+1's) == np.argmin.
  if (tid < 64) {
    float v = s_val[tid];
    int b = s_idx[tid];
#pragma unroll
    for (int c = 1; c < 4; ++c) {
      float vc = s_val[c * 64 + tid];
      if (vc < v) { v = vc; b = s_idx[c * 64 + tid]; }
    }
    s_best[tid] = b;
    out_idx[row] = (float)b;
  }
  __syncthreads();

  // Coalesced output writes: 64 rows x 16 float4 per array.
  const float4* e4v = (const float4*)emb;
  const size_t base4 = (size_t)blockIdx.x * 64 * 16;
  float4* o0 = (float4*)out_st;
  float4* o1 = (float4*)out_q;
#pragma unroll
  for (int t = 0; t < 4; ++t) {
    int i = t * 256 + tid;
    int r = i >> 4, j = i & 15;
    float4 v = e4v[s_best[r] * 16 + j];
    o0[base4 + i] = v;
    o1[base4 + i] = v;
  }
}

extern "C" void kernel_launch(void* const* d_in, const int* in_sizes, int n_in,
                              void* d_out, int out_size, void* d_ws,
                              size_t ws_size, hipStream_t stream) {
  const float* z_e = (const float*)d_in[0];  // [N, D] fp32
  const float* emb = (const float*)d_in[1];  // [K, D] fp32
  float* nrm = (float*)d_ws;                 // [K] fp32 scratch

  float* out_st = (float*)d_out;                 // [N, D]
  float* out_q = out_st + (size_t)VQ_N * VQ_D;   // [N, D]
  float* out_idx = out_q + (size_t)VQ_N * VQ_D;  // [N] as float

  vq_norms_kernel<<<VQ_K / 64, 64, 0, stream>>>(emb, nrm);
  vq_main_kernel<<<VQ_N / 64, 256, 0, stream>>>(z_e, emb, nrm, out_st, out_q,
                                                out_idx);
}